// Round 16
// baseline (369.170 us; speedup 1.0000x reference)
//
#include <hip/hip_runtime.h>
#include <math.h>

#define NHID 64
#define NPB 512          // nodes per bucket (power of two; local id = node & 511)
#define NPB_SHIFT 9
#define MAXB 256         // supports N up to 131072
#define CAP 20480        // entries per bucket region (mean 16384 @ E=3.2M)
#define CHUNK 8192       // edges per k_bucketA chunk

__device__ __forceinline__ float bf_lo(unsigned u) { return __uint_as_float(u << 16); }
__device__ __forceinline__ float bf_hi(unsigned u) { return __uint_as_float(u & 0xffff0000u); }
__device__ __forceinline__ unsigned f2bf(float f) {           // RNE bf16 (top 16 bits)
    unsigned u = __float_as_uint(f);
    return (u + 0x7fffu + ((u >> 16) & 1u)) >> 16;
}

// ---------------------------------------------------------------------------
// K_BUILD (fused): blocks [0, nChunks*2)   -> bucketA (one (chunk,side) each;
//                                             key chunk staged in LDS)
//                  blocks [.., +N*8/256)   -> xcast X->Xb (bf16 rows)
//                  blocks [.., +32)        -> repack Qw->W2
// ---------------------------------------------------------------------------
__global__ __launch_bounds__(256) void k_build(const int* __restrict__ src,
                                               const int* __restrict__ dst,
                                               unsigned int* __restrict__ buf0,
                                               unsigned int* __restrict__ buf1,
                                               int* __restrict__ btail0,
                                               int* __restrict__ btail1,
                                               const float* __restrict__ X,
                                               unsigned* __restrict__ Xb,
                                               const float* __restrict__ Qw,
                                               float* __restrict__ W2,
                                               int E, int nB, int nBucketBlocks,
                                               int nXcastBlocks, int N) {
    __shared__ int h[MAXB], b[MAXB];
    __shared__ int sk[CHUNK];              // staged keys (32KB)
    int bid = blockIdx.x;
    int tid = threadIdx.x;

    if (bid >= nBucketBlocks) {
        int xb = bid - nBucketBlocks;
        if (xb < nXcastBlocks) {
            // ---- xcast: pack X -> Xb bf16, 8 floats/thread ----
            int i = xb * 256 + tid;
            if (i < N * 8) {
                const float4* Xv = (const float4*)X;
                float4 f0 = Xv[(size_t)i * 2];
                float4 f1 = Xv[(size_t)i * 2 + 1];
                uint4 p;
                p.x = f2bf(f0.x) | (f2bf(f0.y) << 16);
                p.y = f2bf(f0.z) | (f2bf(f0.w) << 16);
                p.z = f2bf(f1.x) | (f2bf(f1.y) << 16);
                p.w = f2bf(f1.z) | (f2bf(f1.w) << 16);
                ((uint4*)Xb)[i] = p;
            }
        } else {
            // ---- repack Qw -> W2[64][128] = [A|B] ----
            int i = (xb - nXcastBlocks) * 256 + tid;
            if (i < 8192) {
                int f = i >> 7, c = i & 127;
                float v;
                if (c < 64) v = Qw[(c >> 4) * 2048 + f * 16 + (c & 15)];
                else { int cc = c - 64; v = Qw[(cc >> 4) * 2048 + (64 + f) * 16 + (cc & 15)]; }
                W2[i] = v;
            }
        }
        return;
    }

    // ---- bucketA ----
    int side  = bid & 1;
    int chunk = bid >> 1;
    const int* key = side ? src : dst;
    const int* pay = side ? dst : src;
    unsigned int* buf = side ? buf1 : buf0;
    int* btail = side ? btail1 : btail0;

    for (int i = tid; i < nB; i += 256) h[i] = 0;
    __syncthreads();
    int e0 = chunk * CHUNK;
    // pass 1: histogram + stage keys in LDS
    for (int i = tid; i < CHUNK / 4; i += 256) {
        int e = e0 + i * 4;
        int4 k4;
        if (e + 3 < E) {
            k4 = ((const int4*)(key + e0))[i];
            atomicAdd(&h[k4.x >> NPB_SHIFT], 1);
            atomicAdd(&h[k4.y >> NPB_SHIFT], 1);
            atomicAdd(&h[k4.z >> NPB_SHIFT], 1);
            atomicAdd(&h[k4.w >> NPB_SHIFT], 1);
        } else {
            k4.x = (e     < E) ? key[e]     : 0;
            k4.y = (e + 1 < E) ? key[e + 1] : 0;
            k4.z = (e + 2 < E) ? key[e + 2] : 0;
            k4.w = (e + 3 < E) ? key[e + 3] : 0;
            if (e     < E) atomicAdd(&h[k4.x >> NPB_SHIFT], 1);
            if (e + 1 < E) atomicAdd(&h[k4.y >> NPB_SHIFT], 1);
            if (e + 2 < E) atomicAdd(&h[k4.z >> NPB_SHIFT], 1);
            if (e + 3 < E) atomicAdd(&h[k4.w >> NPB_SHIFT], 1);
        }
        ((int4*)sk)[i] = k4;
    }
    __syncthreads();
    for (int i = tid; i < nB; i += 256) {
        int c = h[i];
        b[i] = c ? atomicAdd(&btail[i], c) : 0;
        h[i] = 0;                    // reuse as rank counter
    }
    __syncthreads();
    // pass 2: scatter (keys from LDS, payload from global)
    for (int i = tid; i < CHUNK / 4; i += 256) {
        int e = e0 + i * 4;
        int4 k4 = ((const int4*)sk)[i];
        if (e + 3 < E) {
            int4 p4 = ((const int4*)(pay + e0))[i];
            int bb, r;
            bb = k4.x >> NPB_SHIFT; r = atomicAdd(&h[bb], 1) + b[bb];
            if (r < CAP) buf[(size_t)bb * CAP + r] = ((unsigned)p4.x << NPB_SHIFT) | (unsigned)(k4.x & (NPB - 1));
            bb = k4.y >> NPB_SHIFT; r = atomicAdd(&h[bb], 1) + b[bb];
            if (r < CAP) buf[(size_t)bb * CAP + r] = ((unsigned)p4.y << NPB_SHIFT) | (unsigned)(k4.y & (NPB - 1));
            bb = k4.z >> NPB_SHIFT; r = atomicAdd(&h[bb], 1) + b[bb];
            if (r < CAP) buf[(size_t)bb * CAP + r] = ((unsigned)p4.z << NPB_SHIFT) | (unsigned)(k4.z & (NPB - 1));
            bb = k4.w >> NPB_SHIFT; r = atomicAdd(&h[bb], 1) + b[bb];
            if (r < CAP) buf[(size_t)bb * CAP + r] = ((unsigned)p4.w << NPB_SHIFT) | (unsigned)(k4.w & (NPB - 1));
        } else {
            int ks[4] = {k4.x, k4.y, k4.z, k4.w};
            for (int j = 0; j < 4; ++j) {
                int e2 = e + j;
                if (e2 < E) {
                    int k = ks[j], p = pay[e2];
                    int bb = k >> NPB_SHIFT;
                    int r = atomicAdd(&h[bb], 1) + b[bb];
                    if (r < CAP) buf[(size_t)bb * CAP + r] = ((unsigned)p << NPB_SHIFT) | (unsigned)(k & (NPB - 1));
                }
            }
        }
    }
}

// ---------------------------------------------------------------------------
// csr_work: one bucket of a per-side CSR build; blockDim must be NPB(512).
// Computes its own bucket offset via an in-block scan over btail (no k_bscan).
// Last bucket writes off[N].
// ---------------------------------------------------------------------------
__device__ void csr_work(const unsigned int* __restrict__ bufb,
                         const int* __restrict__ btail, int nB,
                         int* __restrict__ off, int* __restrict__ csr,
                         int N, int bucket) {
    __shared__ int cnt[NPB];
    __shared__ int scn[NPB];
    __shared__ int cur[NPB];
    int tid = threadIdx.x;          // blockDim == NPB == 512
    // ---- in-block exclusive prefix: boff = sum_{i<bucket} min(btail[i],CAP)
    int v = (tid < nB && tid < bucket) ? min(btail[tid], CAP) : 0;
    scn[tid] = v; __syncthreads();
    for (int o = 1; o < 512; o <<= 1) {
        int t = (tid >= o) ? scn[tid - o] : 0; __syncthreads();
        scn[tid] += t; __syncthreads();
    }
    int boff = scn[511];
    int cnt_b = min(btail[bucket], CAP);
    if (bucket == nB - 1 && tid == 0) off[N] = boff + cnt_b;
    __syncthreads();
    // ---- count / scan / emit / scatter
    cnt[tid] = 0;
    __syncthreads();
    for (int i = tid; i < cnt_b; i += 512)
        atomicAdd(&cnt[bufb[i] & (NPB - 1)], 1);
    __syncthreads();
    v = cnt[tid];
    scn[tid] = v; __syncthreads();
    for (int o = 1; o < 512; o <<= 1) {
        int t = (tid >= o) ? scn[tid - o] : 0; __syncthreads();
        scn[tid] += t; __syncthreads();
    }
    int base = boff + scn[tid] - v;   // exclusive
    cur[tid] = base;
    int node = (bucket << NPB_SHIFT) + tid;
    if (node < N) off[node] = base;
    __syncthreads();
    for (int i = tid; i < cnt_b; i += 512) {
        unsigned int u = bufb[i];
        int pos = atomicAdd(&cur[u & (NPB - 1)], 1);
        csr[pos] = (int)(u >> NPB_SHIFT);
    }
}

// ---------------------------------------------------------------------------
// K_CSR0: side-0 (by dst) CSR build, one bucket per block.
// ---------------------------------------------------------------------------
__global__ __launch_bounds__(512) void k_csr0(const unsigned int* __restrict__ buf0,
                                              const int* __restrict__ btail0,
                                              int* __restrict__ off0,
                                              int* __restrict__ csr0, int N, int nB) {
    int b = blockIdx.x;
    csr_work(buf0 + (size_t)b * CAP, btail0, nB, off0, csr0, N, b);
}

// ---------------------------------------------------------------------------
// K_AGGCSR (fused): blocks [0, nB) -> side-1 CSR build (dispatched FIRST so
// it overlaps the agg memory wall); blocks [nB, nB+aggBlocks) -> agg gather.
// agg[n] written PACKED BF16 [N][64].
// ---------------------------------------------------------------------------
#define AGG_ACC(u) \
    accA.x += bf_lo(u.x); accA.y += bf_hi(u.x); \
    accA.z += bf_lo(u.y); accA.w += bf_hi(u.y); \
    accB.x += bf_lo(u.z); accB.y += bf_hi(u.z); \
    accB.z += bf_lo(u.w); accB.w += bf_hi(u.w);
#define AGG_ACCM(u, f) \
    accA.x += f * bf_lo(u.x); accA.y += f * bf_hi(u.x); \
    accA.z += f * bf_lo(u.y); accA.w += f * bf_hi(u.y); \
    accB.x += f * bf_lo(u.z); accB.y += f * bf_hi(u.z); \
    accB.z += f * bf_lo(u.w); accB.w += f * bf_hi(u.w);

__global__ __launch_bounds__(512) void k_aggcsr(const unsigned* __restrict__ Xb,
                                                const int* __restrict__ off_dst,
                                                const int* __restrict__ csr_dst,
                                                unsigned* __restrict__ aggb,
                                                const unsigned int* __restrict__ buf1,
                                                const int* __restrict__ btail1,
                                                int* __restrict__ off1,
                                                int* __restrict__ csr1,
                                                int N, int nB) {
    int bid = blockIdx.x;
    if (bid < nB) {
        csr_work(buf1 + (size_t)bid * CAP, btail1, nB, off1, csr1, N, bid);
        return;
    }
    int abid = bid - nB;
    int tid = threadIdx.x;
    int lane = tid & 63;
    int node = abid * 8 + (tid >> 6);
    if (node >= N) return;
    int grp = lane >> 3, col8 = lane & 7;
    const uint4* Xb4 = (const uint4*)Xb;          // row n -> Xb4[n*8 + col8]
    int s0 = off_dst[node], s1 = off_dst[node + 1];
    float4 accA = make_float4(0.f, 0.f, 0.f, 0.f);
    float4 accB = make_float4(0.f, 0.f, 0.f, 0.f);
    for (int base = s0; base < s1; base += 64) {
        int cnt = min(64, s1 - base);
        int idx = (base + lane < s1) ? csr_dst[base + lane] : 0;
        int j = 0;
        for (; j + 32 <= cnt; j += 32) {
            int m0 = __shfl(idx, j + grp);
            int m1 = __shfl(idx, j + 8 + grp);
            int m2 = __shfl(idx, j + 16 + grp);
            int m3 = __shfl(idx, j + 24 + grp);
            uint4 u0 = Xb4[(size_t)m0 * 8 + col8];
            uint4 u1 = Xb4[(size_t)m1 * 8 + col8];
            uint4 u2 = Xb4[(size_t)m2 * 8 + col8];
            uint4 u3 = Xb4[(size_t)m3 * 8 + col8];
            AGG_ACC(u0); AGG_ACC(u1); AGG_ACC(u2); AGG_ACC(u3);
        }
        if (j < cnt) {
            int q0 = j + grp, q1 = j + 8 + grp, q2 = j + 16 + grp, q3 = j + 24 + grp;
            int m0 = __shfl(idx, q0);
            int m1 = __shfl(idx, q1);
            int m2 = __shfl(idx, q2);
            int m3 = __shfl(idx, q3);
            float f0 = (q0 < cnt) ? 1.f : 0.f; if (q0 >= cnt) m0 = 0;
            float f1 = (q1 < cnt) ? 1.f : 0.f; if (q1 >= cnt) m1 = 0;
            float f2 = (q2 < cnt) ? 1.f : 0.f; if (q2 >= cnt) m2 = 0;
            float f3 = (q3 < cnt) ? 1.f : 0.f; if (q3 >= cnt) m3 = 0;
            uint4 u0 = Xb4[(size_t)m0 * 8 + col8];
            uint4 u1 = Xb4[(size_t)m1 * 8 + col8];
            uint4 u2 = Xb4[(size_t)m2 * 8 + col8];
            uint4 u3 = Xb4[(size_t)m3 * 8 + col8];
            AGG_ACCM(u0, f0); AGG_ACCM(u1, f1); AGG_ACCM(u2, f2); AGG_ACCM(u3, f3);
        }
    }
    #pragma unroll
    for (int d = 8; d < 64; d <<= 1) {
        accA.x += __shfl_xor(accA.x, d); accA.y += __shfl_xor(accA.y, d);
        accA.z += __shfl_xor(accA.z, d); accA.w += __shfl_xor(accA.w, d);
        accB.x += __shfl_xor(accB.x, d); accB.y += __shfl_xor(accB.y, d);
        accB.z += __shfl_xor(accB.z, d); accB.w += __shfl_xor(accB.w, d);
    }
    if (grp == 0) {
        int deg = s1 - s0;
        float inv = 1.f / (float)max(deg, 1);
        uint4 p;
        p.x = f2bf(accA.x * inv) | (f2bf(accA.y * inv) << 16);
        p.y = f2bf(accA.z * inv) | (f2bf(accA.w * inv) << 16);
        p.z = f2bf(accB.x * inv) | (f2bf(accB.y * inv) << 16);
        p.w = f2bf(accB.z * inv) | (f2bf(accB.w * inv) << 16);
        ((uint4*)aggb)[(size_t)node * 8 + col8] = p;
    }
}

// ---------------------------------------------------------------------------
// K_PHASEAB (fused): 256 threads / 32 nodes, 8 threads per node.
// Phase A: thread computes X2 cols [part*8, part*8+8) -> bf16 -> LDS stage
// (node stride 36 uints: conflict-free broadcast reads).
// Phase B: per current k_phaseB, but X2 read from LDS; W2 in LDS with
// padded-group layout (stride 160 -> zero bank conflicts).
// Eliminates X2b global round-trip + one launch + one weight staging pass.
// LDS = 16+16+40+4.5KB -> 2 blocks/CU.
// ---------------------------------------------------------------------------
__global__ __launch_bounds__(256) void k_phaseAB(const unsigned* __restrict__ Xb,
                                                 const unsigned* __restrict__ aggb,
                                                 const float* __restrict__ Ws,
                                                 const float* __restrict__ Wn,
                                                 const float* __restrict__ bconv,
                                                 const float* __restrict__ W2,
                                                 const float* __restrict__ Qb,
                                                 unsigned* __restrict__ aOut,
                                                 unsigned* __restrict__ bOut, int N) {
    __shared__ float sWs[4096];
    __shared__ float sWn[4096];
    __shared__ float sW2[10240];             // 64 x 160 padded
    __shared__ float sb[64];
    __shared__ unsigned sX2[32 * 36];        // 32 nodes x 32 uints, stride 36
    int tid = threadIdx.x;
    for (int i = tid; i < 4096; i += 256) { sWs[i] = Ws[i]; sWn[i] = Wn[i]; }
    for (int i = tid; i < 8192; i += 256) {
        int f = i >> 7, c = i & 127;
        sW2[f * 160 + (c >> 4) * 20 + (c & 15)] = W2[i];
    }
    if (tid < 64) sb[tid] = bconv[tid];
    __syncthreads();

    int nl = tid >> 3;                  // local node 0..31
    int n = blockIdx.x * 32 + nl;
    int part = tid & 7;
    bool valid = (n < N);

    // ---- phase A: cols [part*8, part*8+8) of X2 = relu(X Ws + agg Wn + b)
    if (valid) {
        const uint4* Xv = (const uint4*)Xb + (size_t)n * 8;
        const uint4* Gv = (const uint4*)aggb + (size_t)n * 8;
        int cb = part * 2;              // float4 col-base
        const float4* ws4 = (const float4*)sWs;
        const float4* wn4 = (const float4*)sWn;
        const float4* bv  = (const float4*)sb;
        float4 a0 = bv[cb], a1 = bv[cb + 1];
        #pragma unroll 2
        for (int q8 = 0; q8 < 8; ++q8) {
            uint4 xu = Xv[q8];
            uint4 gu = Gv[q8];
            float xs[8] = {bf_lo(xu.x), bf_hi(xu.x), bf_lo(xu.y), bf_hi(xu.y),
                           bf_lo(xu.z), bf_hi(xu.z), bf_lo(xu.w), bf_hi(xu.w)};
            float gs[8] = {bf_lo(gu.x), bf_hi(gu.x), bf_lo(gu.y), bf_hi(gu.y),
                           bf_lo(gu.z), bf_hi(gu.z), bf_lo(gu.w), bf_hi(gu.w)};
            #pragma unroll
            for (int j = 0; j < 8; ++j) {
                int k16 = (8 * q8 + j) * 16 + cb;
                float4 w0 = ws4[k16], w1 = ws4[k16 + 1];
                float4 m0 = wn4[k16], m1 = wn4[k16 + 1];
                float xj = xs[j], gj = gs[j];
                a0.x += xj * w0.x + gj * m0.x; a0.y += xj * w0.y + gj * m0.y;
                a0.z += xj * w0.z + gj * m0.z; a0.w += xj * w0.w + gj * m0.w;
                a1.x += xj * w1.x + gj * m1.x; a1.y += xj * w1.y + gj * m1.y;
                a1.z += xj * w1.z + gj * m1.z; a1.w += xj * w1.w + gj * m1.w;
            }
        }
        a0.x = fmaxf(a0.x, 0.f); a0.y = fmaxf(a0.y, 0.f);
        a0.z = fmaxf(a0.z, 0.f); a0.w = fmaxf(a0.w, 0.f);
        a1.x = fmaxf(a1.x, 0.f); a1.y = fmaxf(a1.y, 0.f);
        a1.z = fmaxf(a1.z, 0.f); a1.w = fmaxf(a1.w, 0.f);
        uint4 p;
        p.x = f2bf(a0.x) | (f2bf(a0.y) << 16);
        p.y = f2bf(a0.z) | (f2bf(a0.w) << 16);
        p.z = f2bf(a1.x) | (f2bf(a1.y) << 16);
        p.w = f2bf(a1.z) | (f2bf(a1.w) << 16);
        *((uint4*)(sX2 + nl * 36 + part * 4)) = p;
    }
    __syncthreads();

    // ---- phase B: [a|b] cols [part*16, part*16+16) of the 128 combined
    if (valid) {
        const float4* w4 = (const float4*)sW2;   // row f -> w4[f*40 + part*5 + k]
        float4 a0, a1, a2, a3;
        if (part < 4) {
            const float4* qv = (const float4*)Qb;
            int wb = part << 2;
            a0 = qv[wb]; a1 = qv[wb + 1]; a2 = qv[wb + 2]; a3 = qv[wb + 3];
        } else {
            a0 = a1 = a2 = a3 = make_float4(0.f, 0.f, 0.f, 0.f);
        }
        const uint4* Xv2 = (const uint4*)(sX2 + nl * 36);
        int pbase = part * 5;
        #pragma unroll 2
        for (int q8 = 0; q8 < 8; ++q8) {
            uint4 xu = Xv2[q8];
            float xs[8] = {bf_lo(xu.x), bf_hi(xu.x), bf_lo(xu.y), bf_hi(xu.y),
                           bf_lo(xu.z), bf_hi(xu.z), bf_lo(xu.w), bf_hi(xu.w)};
            #pragma unroll
            for (int j = 0; j < 8; ++j) {
                int b4 = (8 * q8 + j) * 40 + pbase;
                float4 w0 = w4[b4], w1 = w4[b4 + 1], w2 = w4[b4 + 2], w3 = w4[b4 + 3];
                float xj = xs[j];
                a0.x += xj * w0.x; a0.y += xj * w0.y; a0.z += xj * w0.z; a0.w += xj * w0.w;
                a1.x += xj * w1.x; a1.y += xj * w1.y; a1.z += xj * w1.z; a1.w += xj * w1.w;
                a2.x += xj * w2.x; a2.y += xj * w2.y; a2.z += xj * w2.z; a2.w += xj * w2.w;
                a3.x += xj * w3.x; a3.y += xj * w3.y; a3.z += xj * w3.z; a3.w += xj * w3.w;
            }
        }
        uint4 p0, p1;
        p0.x = f2bf(a0.x) | (f2bf(a0.y) << 16);
        p0.y = f2bf(a0.z) | (f2bf(a0.w) << 16);
        p0.z = f2bf(a1.x) | (f2bf(a1.y) << 16);
        p0.w = f2bf(a1.z) | (f2bf(a1.w) << 16);
        p1.x = f2bf(a2.x) | (f2bf(a2.y) << 16);
        p1.y = f2bf(a2.z) | (f2bf(a2.w) << 16);
        p1.z = f2bf(a3.x) | (f2bf(a3.y) << 16);
        p1.w = f2bf(a3.z) | (f2bf(a3.w) << 16);
        uint4* outp = (part < 4) ? (uint4*)aOut + (size_t)n * 8 + part * 2
                                 : (uint4*)bOut + (size_t)n * 8 + (part - 4) * 2;
        outp[0] = p0; outp[1] = p1;
    }
}

// ---------------------------------------------------------------------------
// K6: gg[n,:] = tanh(mean over out-edges of (a[n,:] + b[dst,:])^2)
// a and b both bf16 rows [N][64]; 32 edges/iter = 4 loads in flight.
// ---------------------------------------------------------------------------
#define FIN_ACC(u) { float t; \
    t = avA.x + bf_lo(u.x); accA.x += t * t; \
    t = avA.y + bf_hi(u.x); accA.y += t * t; \
    t = avA.z + bf_lo(u.y); accA.z += t * t; \
    t = avA.w + bf_hi(u.y); accA.w += t * t; \
    t = avB.x + bf_lo(u.z); accB.x += t * t; \
    t = avB.y + bf_hi(u.z); accB.y += t * t; \
    t = avB.z + bf_lo(u.w); accB.z += t * t; \
    t = avB.w + bf_hi(u.w); accB.w += t * t; }
#define FIN_ACCM(u, f) { float t; \
    t = avA.x + bf_lo(u.x); accA.x += f * t * t; \
    t = avA.y + bf_hi(u.x); accA.y += f * t * t; \
    t = avA.z + bf_lo(u.y); accA.z += f * t * t; \
    t = avA.w + bf_hi(u.y); accA.w += f * t * t; \
    t = avB.x + bf_lo(u.z); accB.x += f * t * t; \
    t = avB.y + bf_hi(u.z); accB.y += f * t * t; \
    t = avB.z + bf_lo(u.w); accB.z += f * t * t; \
    t = avB.w + bf_hi(u.w); accB.w += f * t * t; }

__global__ __launch_bounds__(256) void k_final(const unsigned* __restrict__ aFb,
                                               const unsigned* __restrict__ bFb,
                                               const int* __restrict__ off_src,
                                               const int* __restrict__ csr_src,
                                               float* __restrict__ out, int N) {
    int lane = threadIdx.x & 63;
    int node = blockIdx.x * 4 + (threadIdx.x >> 6);
    if (node >= N) return;
    int grp = lane >> 3, col8 = lane & 7;
    const uint4* Bv = (const uint4*)bFb;
    uint4 au = ((const uint4*)aFb)[(size_t)node * 8 + col8];
    float4 avA = make_float4(bf_lo(au.x), bf_hi(au.x), bf_lo(au.y), bf_hi(au.y));
    float4 avB = make_float4(bf_lo(au.z), bf_hi(au.z), bf_lo(au.w), bf_hi(au.w));
    int s0 = off_src[node], s1 = off_src[node + 1];
    float4 accA = make_float4(0.f, 0.f, 0.f, 0.f);
    float4 accB = make_float4(0.f, 0.f, 0.f, 0.f);
    for (int base = s0; base < s1; base += 64) {
        int cnt = min(64, s1 - base);
        int idx = (base + lane < s1) ? csr_src[base + lane] : 0;
        int j = 0;
        for (; j + 32 <= cnt; j += 32) {
            int m0 = __shfl(idx, j + grp);
            int m1 = __shfl(idx, j + 8 + grp);
            int m2 = __shfl(idx, j + 16 + grp);
            int m3 = __shfl(idx, j + 24 + grp);
            uint4 u0 = Bv[(size_t)m0 * 8 + col8];
            uint4 u1 = Bv[(size_t)m1 * 8 + col8];
            uint4 u2 = Bv[(size_t)m2 * 8 + col8];
            uint4 u3 = Bv[(size_t)m3 * 8 + col8];
            FIN_ACC(u0); FIN_ACC(u1); FIN_ACC(u2); FIN_ACC(u3);
        }
        if (j < cnt) {
            int q0 = j + grp, q1 = j + 8 + grp, q2 = j + 16 + grp, q3 = j + 24 + grp;
            int m0 = __shfl(idx, q0);
            int m1 = __shfl(idx, q1);
            int m2 = __shfl(idx, q2);
            int m3 = __shfl(idx, q3);
            float f0 = (q0 < cnt) ? 1.f : 0.f; if (q0 >= cnt) m0 = 0;
            float f1 = (q1 < cnt) ? 1.f : 0.f; if (q1 >= cnt) m1 = 0;
            float f2 = (q2 < cnt) ? 1.f : 0.f; if (q2 >= cnt) m2 = 0;
            float f3 = (q3 < cnt) ? 1.f : 0.f; if (q3 >= cnt) m3 = 0;
            uint4 u0 = Bv[(size_t)m0 * 8 + col8];
            uint4 u1 = Bv[(size_t)m1 * 8 + col8];
            uint4 u2 = Bv[(size_t)m2 * 8 + col8];
            uint4 u3 = Bv[(size_t)m3 * 8 + col8];
            FIN_ACCM(u0, f0); FIN_ACCM(u1, f1); FIN_ACCM(u2, f2); FIN_ACCM(u3, f3);
        }
    }
    #pragma unroll
    for (int d = 8; d < 64; d <<= 1) {
        accA.x += __shfl_xor(accA.x, d); accA.y += __shfl_xor(accA.y, d);
        accA.z += __shfl_xor(accA.z, d); accA.w += __shfl_xor(accA.w, d);
        accB.x += __shfl_xor(accB.x, d); accB.y += __shfl_xor(accB.y, d);
        accB.z += __shfl_xor(accB.z, d); accB.w += __shfl_xor(accB.w, d);
    }
    if (grp == 0) {
        int deg = s1 - s0;
        float inv = 1.f / (float)max(deg, 1);
        float4 r0 = make_float4(tanhf(accA.x * inv), tanhf(accA.y * inv),
                                tanhf(accA.z * inv), tanhf(accA.w * inv));
        float4 r1 = make_float4(tanhf(accB.x * inv), tanhf(accB.y * inv),
                                tanhf(accB.z * inv), tanhf(accB.w * inv));
        ((float4*)out)[(size_t)node * 16 + col8 * 2]     = r0;
        ((float4*)out)[(size_t)node * 16 + col8 * 2 + 1] = r1;
    }
}

// ---------------------------------------------------------------------------
extern "C" void kernel_launch(void* const* d_in, const int* in_sizes, int n_in,
                              void* d_out, int out_size, void* d_ws, size_t ws_size,
                              hipStream_t stream) {
    const float* X      = (const float*)d_in[0];
    const int*   ei     = (const int*)d_in[1];
    const float* Wself  = (const float*)d_in[2];
    const float* Wneigh = (const float*)d_in[3];
    const float* bconv  = (const float*)d_in[4];
    const float* Qw     = (const float*)d_in[5];
    const float* Qb     = (const float*)d_in[6];

    int N = in_sizes[0] / NHID;
    int E = in_sizes[1] / 2;
    const int* src = ei;        // edge_index[0]
    const int* dst = ei + E;    // edge_index[1]
    int nB = (N + NPB - 1) >> NPB_SHIFT;           // 196 for N=100K
    int nChunks = (E + CHUNK - 1) / CHUNK;         // 391 for E=3.2M

    // ---- workspace layout (~120 MB; lifetimes annotated) ----
    char* ws = (char*)d_ws;
    size_t bufBytes = (size_t)MAXB * CAP * 4;      // 21.0 MB per side
    size_t NH2 = (size_t)N * NHID * 2;             // 12.8 MB
    unsigned int* buf0 = (unsigned int*)(ws);
    unsigned int* buf1 = (unsigned int*)(ws + bufBytes);
    unsigned* aFb  = (unsigned*)(ws);                           // after csr builds
    unsigned* bFb  = (unsigned*)(ws + NH2);
    unsigned* Xb   = (unsigned*)(ws + 2 * bufBytes);            // 42 MB
    unsigned* aggb = (unsigned*)(ws + 2 * bufBytes + NH2);
    size_t pos = 2 * bufBytes + 2 * NH2;                        // ~67.6 MB
    pos = (pos + 255) & ~(size_t)255;
    auto alloc = [&](size_t bytes) -> void* {
        void* p = ws + pos;
        pos = (pos + bytes + 255) & ~(size_t)255;
        return p;
    };
    int* csr0   = (int*)alloc((size_t)E * 4);      // by dst
    int* csr1   = (int*)alloc((size_t)E * 4);      // by src
    int* off0   = (int*)alloc((size_t)(N + 1) * 4);
    int* off1   = (int*)alloc((size_t)(N + 1) * 4);
    int* btail0 = (int*)alloc((size_t)MAXB * 4);
    int* btail1 = (int*)alloc((size_t)MAXB * 4);
    float* W2   = (float*)alloc((size_t)8192 * 4); // repacked [A|B], 32KB
    (void)ws_size; (void)n_in; (void)out_size;

    hipMemsetAsync(btail0, 0, (size_t)2 * MAXB * 4, stream);   // btail0+btail1 contiguous

    int nBucketBlocks = nChunks * 2;
    int nXcastBlocks  = (N * 8 + 255) / 256;
    int nBuildBlocks  = nBucketBlocks + nXcastBlocks + 32;
    int aggBlocks     = (N + 7) / 8;

    k_build<<<nBuildBlocks, 256, 0, stream>>>(src, dst, buf0, buf1, btail0, btail1,
                                              X, Xb, Qw, W2,
                                              E, nB, nBucketBlocks, nXcastBlocks, N);
    k_csr0<<<nB, 512, 0, stream>>>(buf0, btail0, off0, csr0, N, nB);
    k_aggcsr<<<nB + aggBlocks, 512, 0, stream>>>(Xb, off0, csr0, aggb,
                                                 buf1, btail1, off1, csr1,
                                                 N, nB);
    k_phaseAB<<<(N + 31) / 32, 256, 0, stream>>>(Xb, aggb, Wself, Wneigh, bconv,
                                                 W2, Qb, aFb, bFb, N);
    k_final<<<(N + 3) / 4, 256, 0, stream>>>(aFb, bFb, off1, csr1, (float*)d_out, N);
}

// Round 17
// 314.931 us; speedup vs baseline: 1.1722x; 1.1722x over previous
//
#include <hip/hip_runtime.h>
#include <math.h>

#define NHID 64
#define NPB 512          // nodes per bucket (power of two; local id = node & 511)
#define NPB_SHIFT 9
#define MAXB 256         // supports N up to 131072
#define CAP 20480        // entries per bucket region (mean 16384 @ E=3.2M)
#define CHUNK 8192       // edges per k_bucketA chunk

__device__ __forceinline__ float bf_lo(unsigned u) { return __uint_as_float(u << 16); }
__device__ __forceinline__ float bf_hi(unsigned u) { return __uint_as_float(u & 0xffff0000u); }
__device__ __forceinline__ unsigned f2bf(float f) {           // RNE bf16 (top 16 bits)
    unsigned u = __float_as_uint(f);
    return (u + 0x7fffu + ((u >> 16) & 1u)) >> 16;
}

// ---------------------------------------------------------------------------
// K_BUILD (fused): blocks [0, nChunks*2)   -> bucketA (one (chunk,side) each;
//                                             key chunk staged in LDS)
//                  blocks [.., +N*8/256)   -> xcast X->Xb (bf16 rows)
//                  blocks [.., +32)        -> repack Qw->W2
// ---------------------------------------------------------------------------
__global__ __launch_bounds__(256) void k_build(const int* __restrict__ src,
                                               const int* __restrict__ dst,
                                               unsigned int* __restrict__ buf0,
                                               unsigned int* __restrict__ buf1,
                                               int* __restrict__ btail0,
                                               int* __restrict__ btail1,
                                               const float* __restrict__ X,
                                               unsigned* __restrict__ Xb,
                                               const float* __restrict__ Qw,
                                               float* __restrict__ W2,
                                               int E, int nB, int nBucketBlocks,
                                               int nXcastBlocks, int N) {
    __shared__ int h[MAXB], b[MAXB];
    __shared__ int sk[CHUNK];              // staged keys (32KB)
    int bid = blockIdx.x;
    int tid = threadIdx.x;

    if (bid >= nBucketBlocks) {
        int xb = bid - nBucketBlocks;
        if (xb < nXcastBlocks) {
            // ---- xcast: pack X -> Xb bf16, 8 floats/thread ----
            int i = xb * 256 + tid;
            if (i < N * 8) {
                const float4* Xv = (const float4*)X;
                float4 f0 = Xv[(size_t)i * 2];
                float4 f1 = Xv[(size_t)i * 2 + 1];
                uint4 p;
                p.x = f2bf(f0.x) | (f2bf(f0.y) << 16);
                p.y = f2bf(f0.z) | (f2bf(f0.w) << 16);
                p.z = f2bf(f1.x) | (f2bf(f1.y) << 16);
                p.w = f2bf(f1.z) | (f2bf(f1.w) << 16);
                ((uint4*)Xb)[i] = p;
            }
        } else {
            // ---- repack Qw -> W2[64][128] = [A|B] ----
            int i = (xb - nXcastBlocks) * 256 + tid;
            if (i < 8192) {
                int f = i >> 7, c = i & 127;
                float v;
                if (c < 64) v = Qw[(c >> 4) * 2048 + f * 16 + (c & 15)];
                else { int cc = c - 64; v = Qw[(cc >> 4) * 2048 + (64 + f) * 16 + (cc & 15)]; }
                W2[i] = v;
            }
        }
        return;
    }

    // ---- bucketA ----
    int side  = bid & 1;
    int chunk = bid >> 1;
    const int* key = side ? src : dst;
    const int* pay = side ? dst : src;
    unsigned int* buf = side ? buf1 : buf0;
    int* btail = side ? btail1 : btail0;

    for (int i = tid; i < nB; i += 256) h[i] = 0;
    __syncthreads();
    int e0 = chunk * CHUNK;
    // pass 1: histogram + stage keys in LDS
    for (int i = tid; i < CHUNK / 4; i += 256) {
        int e = e0 + i * 4;
        int4 k4;
        if (e + 3 < E) {
            k4 = ((const int4*)(key + e0))[i];
            atomicAdd(&h[k4.x >> NPB_SHIFT], 1);
            atomicAdd(&h[k4.y >> NPB_SHIFT], 1);
            atomicAdd(&h[k4.z >> NPB_SHIFT], 1);
            atomicAdd(&h[k4.w >> NPB_SHIFT], 1);
        } else {
            k4.x = (e     < E) ? key[e]     : 0;
            k4.y = (e + 1 < E) ? key[e + 1] : 0;
            k4.z = (e + 2 < E) ? key[e + 2] : 0;
            k4.w = (e + 3 < E) ? key[e + 3] : 0;
            if (e     < E) atomicAdd(&h[k4.x >> NPB_SHIFT], 1);
            if (e + 1 < E) atomicAdd(&h[k4.y >> NPB_SHIFT], 1);
            if (e + 2 < E) atomicAdd(&h[k4.z >> NPB_SHIFT], 1);
            if (e + 3 < E) atomicAdd(&h[k4.w >> NPB_SHIFT], 1);
        }
        ((int4*)sk)[i] = k4;
    }
    __syncthreads();
    for (int i = tid; i < nB; i += 256) {
        int c = h[i];
        b[i] = c ? atomicAdd(&btail[i], c) : 0;
        h[i] = 0;                    // reuse as rank counter
    }
    __syncthreads();
    // pass 2: scatter (keys from LDS, payload from global)
    for (int i = tid; i < CHUNK / 4; i += 256) {
        int e = e0 + i * 4;
        int4 k4 = ((const int4*)sk)[i];
        if (e + 3 < E) {
            int4 p4 = ((const int4*)(pay + e0))[i];
            int bb, r;
            bb = k4.x >> NPB_SHIFT; r = atomicAdd(&h[bb], 1) + b[bb];
            if (r < CAP) buf[(size_t)bb * CAP + r] = ((unsigned)p4.x << NPB_SHIFT) | (unsigned)(k4.x & (NPB - 1));
            bb = k4.y >> NPB_SHIFT; r = atomicAdd(&h[bb], 1) + b[bb];
            if (r < CAP) buf[(size_t)bb * CAP + r] = ((unsigned)p4.y << NPB_SHIFT) | (unsigned)(k4.y & (NPB - 1));
            bb = k4.z >> NPB_SHIFT; r = atomicAdd(&h[bb], 1) + b[bb];
            if (r < CAP) buf[(size_t)bb * CAP + r] = ((unsigned)p4.z << NPB_SHIFT) | (unsigned)(k4.z & (NPB - 1));
            bb = k4.w >> NPB_SHIFT; r = atomicAdd(&h[bb], 1) + b[bb];
            if (r < CAP) buf[(size_t)bb * CAP + r] = ((unsigned)p4.w << NPB_SHIFT) | (unsigned)(k4.w & (NPB - 1));
        } else {
            int ks[4] = {k4.x, k4.y, k4.z, k4.w};
            for (int j = 0; j < 4; ++j) {
                int e2 = e + j;
                if (e2 < E) {
                    int k = ks[j], p = pay[e2];
                    int bb = k >> NPB_SHIFT;
                    int r = atomicAdd(&h[bb], 1) + b[bb];
                    if (r < CAP) buf[(size_t)bb * CAP + r] = ((unsigned)p << NPB_SHIFT) | (unsigned)(k & (NPB - 1));
                }
            }
        }
    }
}

// ---------------------------------------------------------------------------
// csr_work: one bucket of a per-side CSR build; blockDim must be NPB(512).
// Computes its own bucket offset via an in-block scan over btail (no k_bscan).
// Last bucket writes off[N].
// ---------------------------------------------------------------------------
__device__ void csr_work(const unsigned int* __restrict__ bufb,
                         const int* __restrict__ btail, int nB,
                         int* __restrict__ off, int* __restrict__ csr,
                         int N, int bucket) {
    __shared__ int cnt[NPB];
    __shared__ int scn[NPB];
    __shared__ int cur[NPB];
    int tid = threadIdx.x;          // blockDim == NPB == 512
    // ---- in-block exclusive prefix: boff = sum_{i<bucket} min(btail[i],CAP)
    int v = (tid < nB && tid < bucket) ? min(btail[tid], CAP) : 0;
    scn[tid] = v; __syncthreads();
    for (int o = 1; o < 512; o <<= 1) {
        int t = (tid >= o) ? scn[tid - o] : 0; __syncthreads();
        scn[tid] += t; __syncthreads();
    }
    int boff = scn[511];
    int cnt_b = min(btail[bucket], CAP);
    if (bucket == nB - 1 && tid == 0) off[N] = boff + cnt_b;
    __syncthreads();
    // ---- count / scan / emit / scatter
    cnt[tid] = 0;
    __syncthreads();
    for (int i = tid; i < cnt_b; i += 512)
        atomicAdd(&cnt[bufb[i] & (NPB - 1)], 1);
    __syncthreads();
    v = cnt[tid];
    scn[tid] = v; __syncthreads();
    for (int o = 1; o < 512; o <<= 1) {
        int t = (tid >= o) ? scn[tid - o] : 0; __syncthreads();
        scn[tid] += t; __syncthreads();
    }
    int base = boff + scn[tid] - v;   // exclusive
    cur[tid] = base;
    int node = (bucket << NPB_SHIFT) + tid;
    if (node < N) off[node] = base;
    __syncthreads();
    for (int i = tid; i < cnt_b; i += 512) {
        unsigned int u = bufb[i];
        int pos = atomicAdd(&cur[u & (NPB - 1)], 1);
        csr[pos] = (int)(u >> NPB_SHIFT);
    }
}

// ---------------------------------------------------------------------------
// K_CSR0: side-0 (by dst) CSR build, one bucket per block.
// ---------------------------------------------------------------------------
__global__ __launch_bounds__(512) void k_csr0(const unsigned int* __restrict__ buf0,
                                              const int* __restrict__ btail0,
                                              int* __restrict__ off0,
                                              int* __restrict__ csr0, int N, int nB) {
    int b = blockIdx.x;
    csr_work(buf0 + (size_t)b * CAP, btail0, nB, off0, csr0, N, b);
}

// ---------------------------------------------------------------------------
// K_AGGCSR (fused): blocks [0, nB) -> side-1 CSR build (dispatched FIRST so
// it overlaps the agg memory wall); blocks [nB, nB+aggBlocks) -> agg gather.
// agg[n] written PACKED BF16 [N][64].
// ---------------------------------------------------------------------------
#define AGG_ACC(u) \
    accA.x += bf_lo(u.x); accA.y += bf_hi(u.x); \
    accA.z += bf_lo(u.y); accA.w += bf_hi(u.y); \
    accB.x += bf_lo(u.z); accB.y += bf_hi(u.z); \
    accB.z += bf_lo(u.w); accB.w += bf_hi(u.w);
#define AGG_ACCM(u, f) \
    accA.x += f * bf_lo(u.x); accA.y += f * bf_hi(u.x); \
    accA.z += f * bf_lo(u.y); accA.w += f * bf_hi(u.y); \
    accB.x += f * bf_lo(u.z); accB.y += f * bf_hi(u.z); \
    accB.z += f * bf_lo(u.w); accB.w += f * bf_hi(u.w);

__global__ __launch_bounds__(512) void k_aggcsr(const unsigned* __restrict__ Xb,
                                                const int* __restrict__ off_dst,
                                                const int* __restrict__ csr_dst,
                                                unsigned* __restrict__ aggb,
                                                const unsigned int* __restrict__ buf1,
                                                const int* __restrict__ btail1,
                                                int* __restrict__ off1,
                                                int* __restrict__ csr1,
                                                int N, int nB) {
    int bid = blockIdx.x;
    if (bid < nB) {
        csr_work(buf1 + (size_t)bid * CAP, btail1, nB, off1, csr1, N, bid);
        return;
    }
    int abid = bid - nB;
    int tid = threadIdx.x;
    int lane = tid & 63;
    int node = abid * 8 + (tid >> 6);
    if (node >= N) return;
    int grp = lane >> 3, col8 = lane & 7;
    const uint4* Xb4 = (const uint4*)Xb;          // row n -> Xb4[n*8 + col8]
    int s0 = off_dst[node], s1 = off_dst[node + 1];
    float4 accA = make_float4(0.f, 0.f, 0.f, 0.f);
    float4 accB = make_float4(0.f, 0.f, 0.f, 0.f);
    for (int base = s0; base < s1; base += 64) {
        int cnt = min(64, s1 - base);
        int idx = (base + lane < s1) ? csr_dst[base + lane] : 0;
        int j = 0;
        for (; j + 32 <= cnt; j += 32) {
            int m0 = __shfl(idx, j + grp);
            int m1 = __shfl(idx, j + 8 + grp);
            int m2 = __shfl(idx, j + 16 + grp);
            int m3 = __shfl(idx, j + 24 + grp);
            uint4 u0 = Xb4[(size_t)m0 * 8 + col8];
            uint4 u1 = Xb4[(size_t)m1 * 8 + col8];
            uint4 u2 = Xb4[(size_t)m2 * 8 + col8];
            uint4 u3 = Xb4[(size_t)m3 * 8 + col8];
            AGG_ACC(u0); AGG_ACC(u1); AGG_ACC(u2); AGG_ACC(u3);
        }
        if (j < cnt) {
            int q0 = j + grp, q1 = j + 8 + grp, q2 = j + 16 + grp, q3 = j + 24 + grp;
            int m0 = __shfl(idx, q0);
            int m1 = __shfl(idx, q1);
            int m2 = __shfl(idx, q2);
            int m3 = __shfl(idx, q3);
            float f0 = (q0 < cnt) ? 1.f : 0.f; if (q0 >= cnt) m0 = 0;
            float f1 = (q1 < cnt) ? 1.f : 0.f; if (q1 >= cnt) m1 = 0;
            float f2 = (q2 < cnt) ? 1.f : 0.f; if (q2 >= cnt) m2 = 0;
            float f3 = (q3 < cnt) ? 1.f : 0.f; if (q3 >= cnt) m3 = 0;
            uint4 u0 = Xb4[(size_t)m0 * 8 + col8];
            uint4 u1 = Xb4[(size_t)m1 * 8 + col8];
            uint4 u2 = Xb4[(size_t)m2 * 8 + col8];
            uint4 u3 = Xb4[(size_t)m3 * 8 + col8];
            AGG_ACCM(u0, f0); AGG_ACCM(u1, f1); AGG_ACCM(u2, f2); AGG_ACCM(u3, f3);
        }
    }
    #pragma unroll
    for (int d = 8; d < 64; d <<= 1) {
        accA.x += __shfl_xor(accA.x, d); accA.y += __shfl_xor(accA.y, d);
        accA.z += __shfl_xor(accA.z, d); accA.w += __shfl_xor(accA.w, d);
        accB.x += __shfl_xor(accB.x, d); accB.y += __shfl_xor(accB.y, d);
        accB.z += __shfl_xor(accB.z, d); accB.w += __shfl_xor(accB.w, d);
    }
    if (grp == 0) {
        int deg = s1 - s0;
        float inv = 1.f / (float)max(deg, 1);
        uint4 p;
        p.x = f2bf(accA.x * inv) | (f2bf(accA.y * inv) << 16);
        p.y = f2bf(accA.z * inv) | (f2bf(accA.w * inv) << 16);
        p.z = f2bf(accB.x * inv) | (f2bf(accB.y * inv) << 16);
        p.w = f2bf(accB.z * inv) | (f2bf(accB.w * inv) << 16);
        ((uint4*)aggb)[(size_t)node * 8 + col8] = p;
    }
}

// ---------------------------------------------------------------------------
// K5a: X2 = relu(X·Wself + agg·Wneigh + b). Inputs Xb/aggb bf16; weights in
// LDS (16KB -> high occupancy); 4 threads/node. Output X2b PACKED BF16.
// ---------------------------------------------------------------------------
__global__ __launch_bounds__(256) void k_phaseA(const unsigned* __restrict__ Xb,
                                                const unsigned* __restrict__ aggb,
                                                const float* __restrict__ Ws,
                                                const float* __restrict__ Wn,
                                                const float* __restrict__ bconv,
                                                unsigned* __restrict__ X2b, int N) {
    __shared__ float sWs[4096];
    __shared__ float sWn[4096];
    __shared__ float sb[64];
    int tid = threadIdx.x;
    for (int i = tid; i < 4096; i += 256) {
        sWs[i] = Ws[i];
        sWn[i] = Wn[i];
    }
    if (tid < 64) sb[tid] = bconv[tid];
    __syncthreads();

    int n = blockIdx.x * 64 + (tid >> 2);
    if (n >= N) return;
    int wb = (tid & 3) << 2;
    const float4* ws4 = (const float4*)sWs;
    const float4* wn4 = (const float4*)sWn;
    const float4* bv  = (const float4*)sb;
    const uint4* Xv  = (const uint4*)Xb + (size_t)n * 8;
    const uint4* Gv  = (const uint4*)aggb + (size_t)n * 8;
    float4 a0 = bv[wb], a1 = bv[wb + 1], a2 = bv[wb + 2], a3 = bv[wb + 3];
    #pragma unroll 2
    for (int q8 = 0; q8 < 8; ++q8) {
        uint4 xu = Xv[q8];
        uint4 gu = Gv[q8];
        float xs[8] = {bf_lo(xu.x), bf_hi(xu.x), bf_lo(xu.y), bf_hi(xu.y),
                       bf_lo(xu.z), bf_hi(xu.z), bf_lo(xu.w), bf_hi(xu.w)};
        float gs[8] = {bf_lo(gu.x), bf_hi(gu.x), bf_lo(gu.y), bf_hi(gu.y),
                       bf_lo(gu.z), bf_hi(gu.z), bf_lo(gu.w), bf_hi(gu.w)};
        #pragma unroll
        for (int j = 0; j < 8; ++j) {
            int k16 = (8 * q8 + j) * 16 + wb;
            float4 w0 = ws4[k16], w1 = ws4[k16 + 1], w2 = ws4[k16 + 2], w3 = ws4[k16 + 3];
            float4 m0 = wn4[k16], m1 = wn4[k16 + 1], m2 = wn4[k16 + 2], m3 = wn4[k16 + 3];
            float xj = xs[j], gj = gs[j];
            a0.x += xj * w0.x + gj * m0.x; a0.y += xj * w0.y + gj * m0.y;
            a0.z += xj * w0.z + gj * m0.z; a0.w += xj * w0.w + gj * m0.w;
            a1.x += xj * w1.x + gj * m1.x; a1.y += xj * w1.y + gj * m1.y;
            a1.z += xj * w1.z + gj * m1.z; a1.w += xj * w1.w + gj * m1.w;
            a2.x += xj * w2.x + gj * m2.x; a2.y += xj * w2.y + gj * m2.y;
            a2.z += xj * w2.z + gj * m2.z; a2.w += xj * w2.w + gj * m2.w;
            a3.x += xj * w3.x + gj * m3.x; a3.y += xj * w3.y + gj * m3.y;
            a3.z += xj * w3.z + gj * m3.z; a3.w += xj * w3.w + gj * m3.w;
        }
    }
    a0.x = fmaxf(a0.x, 0.f); a0.y = fmaxf(a0.y, 0.f); a0.z = fmaxf(a0.z, 0.f); a0.w = fmaxf(a0.w, 0.f);
    a1.x = fmaxf(a1.x, 0.f); a1.y = fmaxf(a1.y, 0.f); a1.z = fmaxf(a1.z, 0.f); a1.w = fmaxf(a1.w, 0.f);
    a2.x = fmaxf(a2.x, 0.f); a2.y = fmaxf(a2.y, 0.f); a2.z = fmaxf(a2.z, 0.f); a2.w = fmaxf(a2.w, 0.f);
    a3.x = fmaxf(a3.x, 0.f); a3.y = fmaxf(a3.y, 0.f); a3.z = fmaxf(a3.z, 0.f); a3.w = fmaxf(a3.w, 0.f);
    uint4 p0, p1;
    p0.x = f2bf(a0.x) | (f2bf(a0.y) << 16);
    p0.y = f2bf(a0.z) | (f2bf(a0.w) << 16);
    p0.z = f2bf(a1.x) | (f2bf(a1.y) << 16);
    p0.w = f2bf(a1.z) | (f2bf(a1.w) << 16);
    p1.x = f2bf(a2.x) | (f2bf(a2.y) << 16);
    p1.y = f2bf(a2.z) | (f2bf(a2.w) << 16);
    p1.z = f2bf(a3.x) | (f2bf(a3.y) << 16);
    p1.w = f2bf(a3.z) | (f2bf(a3.w) << 16);
    uint4* outp = (uint4*)X2b + (size_t)n * 8 + (tid & 3) * 2;
    outp[0] = p0; outp[1] = p1;
}

// ---------------------------------------------------------------------------
// K5b: [a|b] = X2 · W2 (+[Qb|0]). W2 in LDS with padded-group layout
// (stride 160 -> zero bank conflicts). 8 threads/node; bf16 in/out.
// ---------------------------------------------------------------------------
__global__ __launch_bounds__(256) void k_phaseB(const unsigned* __restrict__ X2b,
                                                const float* __restrict__ W2,
                                                const float* __restrict__ Qb,
                                                unsigned* __restrict__ aOut,
                                                unsigned* __restrict__ bOut, int N) {
    __shared__ float sW[10240];              // 64 rows x 160 floats = 40KB
    int tid = threadIdx.x;
    for (int i = tid; i < 8192; i += 256) {
        int f = i >> 7, c = i & 127;
        sW[f * 160 + (c >> 4) * 20 + (c & 15)] = W2[i];
    }
    __syncthreads();

    int n = blockIdx.x * 32 + (tid >> 3);
    if (n >= N) return;
    int part = tid & 7;                 // 0..3 -> a cols, 4..7 -> b cols
    const float4* w4 = (const float4*)sW;    // row f -> w4[f*40 + part*5 + k]
    float4 a0, a1, a2, a3;
    if (part < 4) {
        const float4* qv = (const float4*)Qb;
        int wb = part << 2;
        a0 = qv[wb]; a1 = qv[wb + 1]; a2 = qv[wb + 2]; a3 = qv[wb + 3];
    } else {
        a0 = a1 = a2 = a3 = make_float4(0.f, 0.f, 0.f, 0.f);
    }
    const uint4* Xv = (const uint4*)X2b + (size_t)n * 8;
    int pbase = part * 5;
    #pragma unroll 2
    for (int q8 = 0; q8 < 8; ++q8) {
        uint4 xu = Xv[q8];
        float xs[8] = {bf_lo(xu.x), bf_hi(xu.x), bf_lo(xu.y), bf_hi(xu.y),
                       bf_lo(xu.z), bf_hi(xu.z), bf_lo(xu.w), bf_hi(xu.w)};
        #pragma unroll
        for (int j = 0; j < 8; ++j) {
            int b4 = (8 * q8 + j) * 40 + pbase;
            float4 w0 = w4[b4], w1 = w4[b4 + 1], w2 = w4[b4 + 2], w3 = w4[b4 + 3];
            float xj = xs[j];
            a0.x += xj * w0.x; a0.y += xj * w0.y; a0.z += xj * w0.z; a0.w += xj * w0.w;
            a1.x += xj * w1.x; a1.y += xj * w1.y; a1.z += xj * w1.z; a1.w += xj * w1.w;
            a2.x += xj * w2.x; a2.y += xj * w2.y; a2.z += xj * w2.z; a2.w += xj * w2.w;
            a3.x += xj * w3.x; a3.y += xj * w3.y; a3.z += xj * w3.z; a3.w += xj * w3.w;
        }
    }
    uint4 p0, p1;
    p0.x = f2bf(a0.x) | (f2bf(a0.y) << 16);
    p0.y = f2bf(a0.z) | (f2bf(a0.w) << 16);
    p0.z = f2bf(a1.x) | (f2bf(a1.y) << 16);
    p0.w = f2bf(a1.z) | (f2bf(a1.w) << 16);
    p1.x = f2bf(a2.x) | (f2bf(a2.y) << 16);
    p1.y = f2bf(a2.z) | (f2bf(a2.w) << 16);
    p1.z = f2bf(a3.x) | (f2bf(a3.y) << 16);
    p1.w = f2bf(a3.z) | (f2bf(a3.w) << 16);
    uint4* outp = (part < 4) ? (uint4*)aOut + (size_t)n * 8 + part * 2
                             : (uint4*)bOut + (size_t)n * 8 + (part - 4) * 2;
    outp[0] = p0; outp[1] = p1;
}

// ---------------------------------------------------------------------------
// K6: gg[n,:] = tanh(mean over out-edges of (a[n,:] + b[dst,:])^2)
// a and b both bf16 rows [N][64]; 32 edges/iter = 4 loads in flight.
// ---------------------------------------------------------------------------
#define FIN_ACC(u) { float t; \
    t = avA.x + bf_lo(u.x); accA.x += t * t; \
    t = avA.y + bf_hi(u.x); accA.y += t * t; \
    t = avA.z + bf_lo(u.y); accA.z += t * t; \
    t = avA.w + bf_hi(u.y); accA.w += t * t; \
    t = avB.x + bf_lo(u.z); accB.x += t * t; \
    t = avB.y + bf_hi(u.z); accB.y += t * t; \
    t = avB.z + bf_lo(u.w); accB.z += t * t; \
    t = avB.w + bf_hi(u.w); accB.w += t * t; }
#define FIN_ACCM(u, f) { float t; \
    t = avA.x + bf_lo(u.x); accA.x += f * t * t; \
    t = avA.y + bf_hi(u.x); accA.y += f * t * t; \
    t = avA.z + bf_lo(u.y); accA.z += f * t * t; \
    t = avA.w + bf_hi(u.y); accA.w += f * t * t; \
    t = avB.x + bf_lo(u.z); accB.x += f * t * t; \
    t = avB.y + bf_hi(u.z); accB.y += f * t * t; \
    t = avB.z + bf_lo(u.w); accB.z += f * t * t; \
    t = avB.w + bf_hi(u.w); accB.w += f * t * t; }

__global__ __launch_bounds__(256) void k_final(const unsigned* __restrict__ aFb,
                                               const unsigned* __restrict__ bFb,
                                               const int* __restrict__ off_src,
                                               const int* __restrict__ csr_src,
                                               float* __restrict__ out, int N) {
    int lane = threadIdx.x & 63;
    int node = blockIdx.x * 4 + (threadIdx.x >> 6);
    if (node >= N) return;
    int grp = lane >> 3, col8 = lane & 7;
    const uint4* Bv = (const uint4*)bFb;
    uint4 au = ((const uint4*)aFb)[(size_t)node * 8 + col8];
    float4 avA = make_float4(bf_lo(au.x), bf_hi(au.x), bf_lo(au.y), bf_hi(au.y));
    float4 avB = make_float4(bf_lo(au.z), bf_hi(au.z), bf_lo(au.w), bf_hi(au.w));
    int s0 = off_src[node], s1 = off_src[node + 1];
    float4 accA = make_float4(0.f, 0.f, 0.f, 0.f);
    float4 accB = make_float4(0.f, 0.f, 0.f, 0.f);
    for (int base = s0; base < s1; base += 64) {
        int cnt = min(64, s1 - base);
        int idx = (base + lane < s1) ? csr_src[base + lane] : 0;
        int j = 0;
        for (; j + 32 <= cnt; j += 32) {
            int m0 = __shfl(idx, j + grp);
            int m1 = __shfl(idx, j + 8 + grp);
            int m2 = __shfl(idx, j + 16 + grp);
            int m3 = __shfl(idx, j + 24 + grp);
            uint4 u0 = Bv[(size_t)m0 * 8 + col8];
            uint4 u1 = Bv[(size_t)m1 * 8 + col8];
            uint4 u2 = Bv[(size_t)m2 * 8 + col8];
            uint4 u3 = Bv[(size_t)m3 * 8 + col8];
            FIN_ACC(u0); FIN_ACC(u1); FIN_ACC(u2); FIN_ACC(u3);
        }
        if (j < cnt) {
            int q0 = j + grp, q1 = j + 8 + grp, q2 = j + 16 + grp, q3 = j + 24 + grp;
            int m0 = __shfl(idx, q0);
            int m1 = __shfl(idx, q1);
            int m2 = __shfl(idx, q2);
            int m3 = __shfl(idx, q3);
            float f0 = (q0 < cnt) ? 1.f : 0.f; if (q0 >= cnt) m0 = 0;
            float f1 = (q1 < cnt) ? 1.f : 0.f; if (q1 >= cnt) m1 = 0;
            float f2 = (q2 < cnt) ? 1.f : 0.f; if (q2 >= cnt) m2 = 0;
            float f3 = (q3 < cnt) ? 1.f : 0.f; if (q3 >= cnt) m3 = 0;
            uint4 u0 = Bv[(size_t)m0 * 8 + col8];
            uint4 u1 = Bv[(size_t)m1 * 8 + col8];
            uint4 u2 = Bv[(size_t)m2 * 8 + col8];
            uint4 u3 = Bv[(size_t)m3 * 8 + col8];
            FIN_ACCM(u0, f0); FIN_ACCM(u1, f1); FIN_ACCM(u2, f2); FIN_ACCM(u3, f3);
        }
    }
    #pragma unroll
    for (int d = 8; d < 64; d <<= 1) {
        accA.x += __shfl_xor(accA.x, d); accA.y += __shfl_xor(accA.y, d);
        accA.z += __shfl_xor(accA.z, d); accA.w += __shfl_xor(accA.w, d);
        accB.x += __shfl_xor(accB.x, d); accB.y += __shfl_xor(accB.y, d);
        accB.z += __shfl_xor(accB.z, d); accB.w += __shfl_xor(accB.w, d);
    }
    if (grp == 0) {
        int deg = s1 - s0;
        float inv = 1.f / (float)max(deg, 1);
        float4 r0 = make_float4(tanhf(accA.x * inv), tanhf(accA.y * inv),
                                tanhf(accA.z * inv), tanhf(accA.w * inv));
        float4 r1 = make_float4(tanhf(accB.x * inv), tanhf(accB.y * inv),
                                tanhf(accB.z * inv), tanhf(accB.w * inv));
        ((float4*)out)[(size_t)node * 16 + col8 * 2]     = r0;
        ((float4*)out)[(size_t)node * 16 + col8 * 2 + 1] = r1;
    }
}

// ---------------------------------------------------------------------------
extern "C" void kernel_launch(void* const* d_in, const int* in_sizes, int n_in,
                              void* d_out, int out_size, void* d_ws, size_t ws_size,
                              hipStream_t stream) {
    const float* X      = (const float*)d_in[0];
    const int*   ei     = (const int*)d_in[1];
    const float* Wself  = (const float*)d_in[2];
    const float* Wneigh = (const float*)d_in[3];
    const float* bconv  = (const float*)d_in[4];
    const float* Qw     = (const float*)d_in[5];
    const float* Qb     = (const float*)d_in[6];

    int N = in_sizes[0] / NHID;
    int E = in_sizes[1] / 2;
    const int* src = ei;        // edge_index[0]
    const int* dst = ei + E;    // edge_index[1]
    int nB = (N + NPB - 1) >> NPB_SHIFT;           // 196 for N=100K
    int nChunks = (E + CHUNK - 1) / CHUNK;         // 391 for E=3.2M

    // ---- workspace layout (~120 MB; lifetimes annotated) ----
    // buf0/buf1 [0,42MB): dead after k_csr0 / k_aggcsr's csr part.
    // X2b/aFb/bFb [0,38.4MB): written by phaseA/phaseB (buf dead by then).
    // Xb/aggb at [42,67.6MB): live alongside buf.
    char* ws = (char*)d_ws;
    size_t bufBytes = (size_t)MAXB * CAP * 4;      // 21.0 MB per side
    size_t NH2 = (size_t)N * NHID * 2;             // 12.8 MB
    unsigned int* buf0 = (unsigned int*)(ws);
    unsigned int* buf1 = (unsigned int*)(ws + bufBytes);
    unsigned* X2b  = (unsigned*)(ws);                           // after csr builds
    unsigned* aFb  = (unsigned*)(ws + NH2);
    unsigned* bFb  = (unsigned*)(ws + 2 * NH2);
    unsigned* Xb   = (unsigned*)(ws + 2 * bufBytes);            // 42 MB
    unsigned* aggb = (unsigned*)(ws + 2 * bufBytes + NH2);
    size_t pos = 2 * bufBytes + 2 * NH2;                        // ~67.6 MB
    pos = (pos + 255) & ~(size_t)255;
    auto alloc = [&](size_t bytes) -> void* {
        void* p = ws + pos;
        pos = (pos + bytes + 255) & ~(size_t)255;
        return p;
    };
    int* csr0   = (int*)alloc((size_t)E * 4);      // by dst
    int* csr1   = (int*)alloc((size_t)E * 4);      // by src
    int* off0   = (int*)alloc((size_t)(N + 1) * 4);
    int* off1   = (int*)alloc((size_t)(N + 1) * 4);
    int* btail0 = (int*)alloc((size_t)MAXB * 4);
    int* btail1 = (int*)alloc((size_t)MAXB * 4);
    float* W2   = (float*)alloc((size_t)8192 * 4); // repacked [A|B], 32KB
    (void)ws_size; (void)n_in; (void)out_size;

    hipMemsetAsync(btail0, 0, (size_t)2 * MAXB * 4, stream);   // btail0+btail1 contiguous

    int nBucketBlocks = nChunks * 2;
    int nXcastBlocks  = (N * 8 + 255) / 256;
    int nBuildBlocks  = nBucketBlocks + nXcastBlocks + 32;
    int aggBlocks     = (N + 7) / 8;

    k_build<<<nBuildBlocks, 256, 0, stream>>>(src, dst, buf0, buf1, btail0, btail1,
                                              X, Xb, Qw, W2,
                                              E, nB, nBucketBlocks, nXcastBlocks, N);
    k_csr0<<<nB, 512, 0, stream>>>(buf0, btail0, off0, csr0, N, nB);
    k_aggcsr<<<nB + aggBlocks, 512, 0, stream>>>(Xb, off0, csr0, aggb,
                                                 buf1, btail1, off1, csr1,
                                                 N, nB);
    k_phaseA<<<(N + 63) / 64, 256, 0, stream>>>(Xb, aggb, Wself, Wneigh, bconv, X2b, N);
    k_phaseB<<<(N + 31) / 32, 256, 0, stream>>>(X2b, W2, Qb, aFb, bFb, N);
    k_final<<<(N + 3) / 4, 256, 0, stream>>>(aFb, bFb, off1, csr1, (float*)d_out, N);
}